// Round 13
// baseline (868.022 us; speedup 1.0000x reference)
//
#include <hip/hip_runtime.h>
#include <stdint.h>

#define NODES 60000
#define NPAD  60032   // 469 * 128
#define EDGES 240000
#define KDIM  768
#define HF    768     // HEADS * F_OUT
#define FOUT  128
#define SCAN_B 59     // ceil(NODES/1024)

typedef unsigned short u16;
typedef __bf16 bf16x8 __attribute__((ext_vector_type(8)));
typedef float f32x4 __attribute__((ext_vector_type(4)));

__device__ __forceinline__ float bf2f(u16 u) {
  union { uint32_t i; float f; } v; v.i = ((uint32_t)u) << 16; return v.f;
}
__device__ __forceinline__ u16 f2bf(float f) {
  union { float f; uint32_t i; } v; v.f = f;
  return (u16)((v.i + 0x7FFF + ((v.i >> 16) & 1)) >> 16);
}

// ---------------- convert x (f32 -> bf16, zero pad rows) ----------------
__global__ __launch_bounds__(256) void convert_x_k(const float* __restrict__ x, u16* __restrict__ xb) {
  const size_t g = ((size_t)blockIdx.x * 256 + threadIdx.x) * 4;
  if (g >= (size_t)NPAD * KDIM) return;
  ushort4 o;
  if (g < (size_t)NODES * KDIM) {
    const float4 v = *(const float4*)(x + g);
    o.x = f2bf(v.x); o.y = f2bf(v.y); o.z = f2bf(v.z); o.w = f2bf(v.w);
  } else { o.x = o.y = o.z = o.w = 0; }
  *(ushort4*)(xb + g) = o;
}

// ---------------- weight prep (LDS-tiled transpose) ----------------
// MODE 0: WT[n][k] = [W | skip][k][n], n<1536
// MODE 1: WT[n][k] = n<768 ? W[k][n] : mean_h skip[k][h*128 + (n-768)], n<896
template <int MODE>
__global__ __launch_bounds__(256) void prep_wcat_k(const float* __restrict__ W, const float* __restrict__ SK,
                                                   u16* __restrict__ WT) {
  __shared__ u16 tile[32][33];
  const int n0 = blockIdx.x * 32, k0 = blockIdx.y * 32;
  const int tx = threadIdx.x & 31, ty = threadIdx.x >> 5;  // 32 x 8
#pragma unroll
  for (int r = 0; r < 32; r += 8) {
    const int k = k0 + ty + r, n = n0 + tx;
    float v;
    if (n < HF) {
      v = W[(size_t)k * HF + n];
    } else if (MODE == 0) {
      v = SK[(size_t)k * HF + (n - HF)];
    } else {
      const int f = n - HF;
      v = 0.f;
#pragma unroll
      for (int h = 0; h < 6; ++h) v += SK[(size_t)k * HF + h * FOUT + f];
      v *= (1.0f / 6.0f);
    }
    tile[ty + r][tx] = f2bf(v);
  }
  __syncthreads();
#pragma unroll
  for (int r = 0; r < 32; r += 8) {
    const int n = n0 + ty + r, k = k0 + tx;
    WT[(size_t)n * KDIM + k] = tile[tx][ty + r];
  }
}

// ---------------- CSR build ----------------
__global__ __launch_bounds__(256) void hist_k(const int* __restrict__ tgt, int* __restrict__ deg) {
  const int e = blockIdx.x * 256 + threadIdx.x;
  if (e < EDGES) atomicAdd(&deg[tgt[e]], 1);
}

// 3-kernel coalesced scan: per-block Hillis-Steele -> scan block totals -> add offsets
__global__ __launch_bounds__(1024) void scan1_k(const int* __restrict__ deg, int* __restrict__ rp,
                                                int* __restrict__ partial) {
  __shared__ int buf[1024];
  const int tid = threadIdx.x;
  const int i = blockIdx.x * 1024 + tid;
  const int v = (i < NODES) ? deg[i] : 0;
  buf[tid] = v;
  __syncthreads();
  for (int off = 1; off < 1024; off <<= 1) {
    const int t = (tid >= off) ? buf[tid - off] : 0;
    __syncthreads();
    buf[tid] += t;
    __syncthreads();
  }
  if (i < NODES) rp[i] = buf[tid] - v;  // local exclusive
  if (tid == 1023) partial[blockIdx.x] = buf[1023];
}

__global__ __launch_bounds__(64) void scan2_k(int* __restrict__ partial, int* __restrict__ rpN) {
  __shared__ int buf[64];
  const int tid = threadIdx.x;
  const int v = (tid < SCAN_B) ? partial[tid] : 0;
  buf[tid] = v;
  __syncthreads();
  for (int off = 1; off < 64; off <<= 1) {
    const int t = (tid >= off) ? buf[tid - off] : 0;
    __syncthreads();
    buf[tid] += t;
    __syncthreads();
  }
  if (tid < SCAN_B) partial[tid] = buf[tid] - v;  // exclusive block offsets
  if (tid == 63) *rpN = buf[63];                  // total edge count
}

__global__ __launch_bounds__(1024) void scan3_k(int* __restrict__ rp, const int* __restrict__ partial,
                                                int* __restrict__ cur) {
  const int i = blockIdx.x * 1024 + threadIdx.x;
  if (i < NODES) {
    const int v = rp[i] + partial[blockIdx.x];
    rp[i] = v;
    cur[i] = v;
  }
}

__global__ __launch_bounds__(256) void scatter_k(const int* __restrict__ srcv, const int* __restrict__ tgt,
                                                 int* __restrict__ cur, int* __restrict__ esrc) {
  const int e = blockIdx.x * 256 + threadIdx.x;
  if (e < EDGES) {
    const int t = tgt[e];
    const int pos = atomicAdd(&cur[t], 1);
    esrc[pos] = srcv[e];
  }
}

// ---------------- bf16 MFMA GEMM + fused attention-score epilogue (R4/R10-proven) ----------------
// 128x128 block, 4 waves (2x2 of 64x64). VGPR 64 + 64 AGPR = 128 -> 4 waves/SIMD.
// LDS-read-BW bound at this geometry (B/FLOP = (64+64)/(64*64)); structure ceiling.
__global__ __launch_bounds__(256, 4) void gemm_k(const u16* __restrict__ A, const u16* __restrict__ BT,
                                                 u16* __restrict__ C,
                                                 const float* __restrict__ a_src, const float* __restrict__ a_tgt,
                                                 float* __restrict__ ss, float* __restrict__ stg,
                                                 int nbx, int ncat) {
  __shared__ u16 As[2][4096];
  __shared__ u16 Bs[2][4096];
  float* sp = (float*)&As[0][0];
  const int tid = threadIdx.x;
  const int lane = tid & 63;
  const int w = tid >> 6;
  const int wm = w >> 1, wn = w & 1;
  const int r16 = lane & 15, g4 = lane >> 4;

  const int NWG = nbx * 469;
  const int q = NWG >> 3, rr = NWG & 7;
  const int orig = blockIdx.x;
  const int xcd = orig & 7, idx = orig >> 3;
  const int wg = (xcd < rr ? xcd * (q + 1) : rr * (q + 1) + (xcd - rr) * q) + idx;
  const int bx = wg % nbx, by = wg / nbx;

  const size_t rowBase = (size_t)by * 128;
  const int colBase = bx * 128;

  const int c0 = tid, c1 = tid + 256;
  const size_t aoff0 = (rowBase + (c0 >> 2)) * KDIM + (c0 & 3) * 8;
  const size_t aoff1 = (rowBase + (c1 >> 2)) * KDIM + (c1 & 3) * 8;
  const size_t boff0 = ((size_t)(colBase + (c0 >> 2))) * KDIM + (c0 & 3) * 8;
  const size_t boff1 = ((size_t)(colBase + (c1 >> 2))) * KDIM + (c1 & 3) * 8;

  auto stage = [&](int buf, int k0) {
    __builtin_amdgcn_global_load_lds((__attribute__((address_space(1))) void*)(A + aoff0 + k0),
                                     (__attribute__((address_space(3))) void*)(&As[buf][w * 512]), 16, 0, 0);
    __builtin_amdgcn_global_load_lds((__attribute__((address_space(1))) void*)(A + aoff1 + k0),
                                     (__attribute__((address_space(3))) void*)(&As[buf][2048 + w * 512]), 16, 0, 0);
    __builtin_amdgcn_global_load_lds((__attribute__((address_space(1))) void*)(BT + boff0 + k0),
                                     (__attribute__((address_space(3))) void*)(&Bs[buf][w * 512]), 16, 0, 0);
    __builtin_amdgcn_global_load_lds((__attribute__((address_space(1))) void*)(BT + boff1 + k0),
                                     (__attribute__((address_space(3))) void*)(&Bs[buf][2048 + w * 512]), 16, 0, 0);
  };

  f32x4 acc[4][4];
#pragma unroll
  for (int i = 0; i < 4; ++i)
#pragma unroll
    for (int j = 0; j < 4; ++j) acc[i][j] = f32x4{0.f, 0.f, 0.f, 0.f};

  stage(0, 0);
  __syncthreads();
  for (int ks = 0; ks < 24; ++ks) {
    const int buf = ks & 1;
    if (ks < 23) stage(buf ^ 1, (ks + 1) * 32);
    bf16x8 af[4], bv[4];
#pragma unroll
    for (int i = 0; i < 4; ++i)
      af[i] = *(const bf16x8*)(&As[buf][(wm * 64 + i * 16 + r16) * 32 + g4 * 8]);
#pragma unroll
    for (int j = 0; j < 4; ++j)
      bv[j] = *(const bf16x8*)(&Bs[buf][(wn * 64 + j * 16 + r16) * 32 + g4 * 8]);
#pragma unroll
    for (int i = 0; i < 4; ++i)
#pragma unroll
      for (int j = 0; j < 4; ++j)
        acc[i][j] = __builtin_amdgcn_mfma_f32_16x16x32_bf16(af[i], bv[j], acc[i][j], 0, 0, 0);
    __syncthreads();
  }

#pragma unroll
  for (int i = 0; i < 4; ++i) {
    const size_t row0 = rowBase + wm * 64 + i * 16 + g4 * 4;
#pragma unroll
    for (int j = 0; j < 4; ++j) {
      const int col = colBase + wn * 64 + j * 16 + r16;
#pragma unroll
      for (int r = 0; r < 4; ++r)
        C[(row0 + r) * ncat + col] = f2bf(acc[i][j][r]);
    }
  }

  if (bx < 6) {
#pragma unroll
    for (int pass = 0; pass < 2; ++pass) {
      const float* av = (pass == 0) ? a_src : a_tgt;
      float a4[4];
#pragma unroll
      for (int j = 0; j < 4; ++j) a4[j] = av[bx * FOUT + wn * 64 + j * 16 + r16];
#pragma unroll
      for (int i = 0; i < 4; ++i) {
#pragma unroll
        for (int r = 0; r < 4; ++r) {
          float p = 0.f;
#pragma unroll
          for (int j = 0; j < 4; ++j) p += acc[i][j][r] * a4[j];
#pragma unroll
          for (int off = 1; off < 16; off <<= 1) p += __shfl_xor(p, off, 64);
          if (r16 == 0) {
            const int row = wm * 64 + i * 16 + g4 * 4 + r;
            sp[pass * 256 + wn * 128 + row] = p;
          }
        }
      }
    }
    __syncthreads();
    if (tid < 128) {
      const size_t row = rowBase + tid;
      if (row < NODES) {
        ss[row * 6 + bx] = sp[tid] + sp[128 + tid];
        stg[row * 6 + bx] = sp[256 + tid] + sp[384 + tid];
      }
    }
  }
}

// ---------------- fused ONLINE-softmax aggregation: one wave per target node, 4-edge unroll ----------------
// lane covers cols {lane*4 + 256k + c : k<3, c<4}; head(col) = (lane>>5) + 2k
// Running (m,d,macc) per head; defer-max: rescale only when group-max exceeds m+8 (ev bounded by e^8).
// 4-edge unroll: 12 independent 8B gathers in flight per iteration (regime test: latency vs L3-BW bound).
template <int MODE>
__global__ __launch_bounds__(256) void aggregate_k(const u16* __restrict__ Cb, const int* __restrict__ rp,
                                                   const int* __restrict__ esrc,
                                                   const float* __restrict__ ss, const float* __restrict__ stg,
                                                   const float* __restrict__ bias,
                                                   u16* __restrict__ xnext, float* __restrict__ outf) {
  constexpr int ncat = (MODE == 0) ? 1536 : 896;
  const int t = blockIdx.x * 4 + (threadIdx.x >> 6);
  const int lane = threadIdx.x & 63;
  if (t >= NODES) return;
  const int l4 = lane * 4;
  const int h0 = lane >> 5;

  const int b = rp[t], e = rp[t + 1];

  float sth[3], m[3], d[3], macc[3][4];
#pragma unroll
  for (int k = 0; k < 3; ++k) {
    sth[k] = stg[t * 6 + h0 + 2 * k];
    m[k] = -1e30f;
    d[k] = 0.f;
#pragma unroll
    for (int c = 0; c < 4; ++c) macc[k][c] = 0.f;
  }

  int j = b;
  for (; j + 3 < e; j += 4) {
    const int s0 = esrc[j], s1 = esrc[j + 1], s2 = esrc[j + 2], s3 = esrc[j + 3];
    const u16* pr0 = Cb + (size_t)s0 * ncat;
    const u16* pr1 = Cb + (size_t)s1 * ncat;
    const u16* pr2 = Cb + (size_t)s2 * ncat;
    const u16* pr3 = Cb + (size_t)s3 * ncat;
#pragma unroll
    for (int k = 0; k < 3; ++k) {
      const ushort4 v0 = *(const ushort4*)(pr0 + l4 + 256 * k);
      const ushort4 v1 = *(const ushort4*)(pr1 + l4 + 256 * k);
      const ushort4 v2 = *(const ushort4*)(pr2 + l4 + 256 * k);
      const ushort4 v3 = *(const ushort4*)(pr3 + l4 + 256 * k);
      float sc0 = ss[s0 * 6 + h0 + 2 * k] + sth[k];
      float sc1 = ss[s1 * 6 + h0 + 2 * k] + sth[k];
      float sc2 = ss[s2 * 6 + h0 + 2 * k] + sth[k];
      float sc3 = ss[s3 * 6 + h0 + 2 * k] + sth[k];
      sc0 = sc0 > 0.f ? sc0 : 0.2f * sc0;
      sc1 = sc1 > 0.f ? sc1 : 0.2f * sc1;
      sc2 = sc2 > 0.f ? sc2 : 0.2f * sc2;
      sc3 = sc3 > 0.f ? sc3 : 0.2f * sc3;
      const float pm = fmaxf(fmaxf(sc0, sc1), fmaxf(sc2, sc3));
      if (pm > m[k] + 8.f) {
        const float r = __expf(m[k] - pm);
        d[k] *= r;
        macc[k][0] *= r; macc[k][1] *= r; macc[k][2] *= r; macc[k][3] *= r;
        m[k] = pm;
      }
      const float ev0 = __expf(sc0 - m[k]);
      const float ev1 = __expf(sc1 - m[k]);
      const float ev2 = __expf(sc2 - m[k]);
      const float ev3 = __expf(sc3 - m[k]);
      d[k] += (ev0 + ev1) + (ev2 + ev3);
      macc[k][0] += ev0 * bf2f(v0.x) + ev1 * bf2f(v1.x) + ev2 * bf2f(v2.x) + ev3 * bf2f(v3.x);
      macc[k][1] += ev0 * bf2f(v0.y) + ev1 * bf2f(v1.y) + ev2 * bf2f(v2.y) + ev3 * bf2f(v3.y);
      macc[k][2] += ev0 * bf2f(v0.z) + ev1 * bf2f(v1.z) + ev2 * bf2f(v2.z) + ev3 * bf2f(v3.z);
      macc[k][3] += ev0 * bf2f(v0.w) + ev1 * bf2f(v1.w) + ev2 * bf2f(v2.w) + ev3 * bf2f(v3.w);
    }
  }
  for (; j + 1 < e; j += 2) {
    const int s0 = esrc[j], s1 = esrc[j + 1];
    const u16* pr0 = Cb + (size_t)s0 * ncat;
    const u16* pr1 = Cb + (size_t)s1 * ncat;
#pragma unroll
    for (int k = 0; k < 3; ++k) {
      const ushort4 v0 = *(const ushort4*)(pr0 + l4 + 256 * k);
      const ushort4 v1 = *(const ushort4*)(pr1 + l4 + 256 * k);
      float sc0 = ss[s0 * 6 + h0 + 2 * k] + sth[k];
      float sc1 = ss[s1 * 6 + h0 + 2 * k] + sth[k];
      sc0 = sc0 > 0.f ? sc0 : 0.2f * sc0;
      sc1 = sc1 > 0.f ? sc1 : 0.2f * sc1;
      const float pm = fmaxf(sc0, sc1);
      if (pm > m[k] + 8.f) {
        const float r = __expf(m[k] - pm);
        d[k] *= r;
        macc[k][0] *= r; macc[k][1] *= r; macc[k][2] *= r; macc[k][3] *= r;
        m[k] = pm;
      }
      const float ev0 = __expf(sc0 - m[k]);
      const float ev1 = __expf(sc1 - m[k]);
      d[k] += ev0 + ev1;
      macc[k][0] += ev0 * bf2f(v0.x) + ev1 * bf2f(v1.x);
      macc[k][1] += ev0 * bf2f(v0.y) + ev1 * bf2f(v1.y);
      macc[k][2] += ev0 * bf2f(v0.z) + ev1 * bf2f(v1.z);
      macc[k][3] += ev0 * bf2f(v0.w) + ev1 * bf2f(v1.w);
    }
  }
  if (j < e) {
    const int s0 = esrc[j];
    const u16* pr0 = Cb + (size_t)s0 * ncat;
#pragma unroll
    for (int k = 0; k < 3; ++k) {
      const ushort4 v0 = *(const ushort4*)(pr0 + l4 + 256 * k);
      float sc0 = ss[s0 * 6 + h0 + 2 * k] + sth[k];
      sc0 = sc0 > 0.f ? sc0 : 0.2f * sc0;
      if (sc0 > m[k] + 8.f) {
        const float r = __expf(m[k] - sc0);
        d[k] *= r;
        macc[k][0] *= r; macc[k][1] *= r; macc[k][2] *= r; macc[k][3] *= r;
        m[k] = sc0;
      }
      const float ev0 = __expf(sc0 - m[k]);
      d[k] += ev0;
      macc[k][0] += ev0 * bf2f(v0.x);
      macc[k][1] += ev0 * bf2f(v0.y);
      macc[k][2] += ev0 * bf2f(v0.z);
      macc[k][3] += ev0 * bf2f(v0.w);
    }
  }

  float inv[3];
#pragma unroll
  for (int k = 0; k < 3; ++k) inv[k] = 1.f / (d[k] + 1e-16f);

  if (MODE == 0) {
    const u16* sk = Cb + (size_t)t * ncat + HF;
#pragma unroll
    for (int k = 0; k < 3; ++k) {
      const ushort4 s4 = *(const ushort4*)(sk + l4 + 256 * k);
      ushort4 o;
      float v0 = macc[k][0] * inv[k] + bf2f(s4.x) + bias[l4 + 256 * k];
      float v1 = macc[k][1] * inv[k] + bf2f(s4.y) + bias[l4 + 256 * k + 1];
      float v2 = macc[k][2] * inv[k] + bf2f(s4.z) + bias[l4 + 256 * k + 2];
      float v3 = macc[k][3] * inv[k] + bf2f(s4.w) + bias[l4 + 256 * k + 3];
      o.x = f2bf(v0 > 0.f ? v0 : expm1f(v0));
      o.y = f2bf(v1 > 0.f ? v1 : expm1f(v1));
      o.z = f2bf(v2 > 0.f ? v2 : expm1f(v2));
      o.w = f2bf(v3 > 0.f ? v3 : expm1f(v3));
      *(ushort4*)(xnext + (size_t)t * HF + l4 + 256 * k) = o;
    }
  } else {
    float4 o;
    float* op = &o.x;
#pragma unroll
    for (int c = 0; c < 4; ++c) {
      const float s3 = macc[0][c] * inv[0] + macc[1][c] * inv[1] + macc[2][c] * inv[2];
      const float tot = s3 + __shfl_xor(s3, 32, 64);
      op[c] = tot * (1.0f / 6.0f);
    }
    if (lane < 32) {
      const int f = lane * 4;
      const ushort4 s4 = *(const ushort4*)(Cb + (size_t)t * ncat + HF + f);
      o.x += bf2f(s4.x) + bias[f];
      o.y += bf2f(s4.y) + bias[f + 1];
      o.z += bf2f(s4.z) + bias[f + 2];
      o.w += bf2f(s4.w) + bias[f + 3];
      *(float4*)(outf + (size_t)t * FOUT + f) = o;
    }
  }
}

// ---------------- workspace layout ----------------
#define OFF_XBF 0ull
#define OFF_CB  92209152ull
#define OFF_WT  276627456ull   // scan partials alias it during CSR build
#define OFF_SS  279023616ull
#define OFF_ST  280463616ull
#define OFF_RP  287663616ull
#define OFF_CUR 287903744ull
#define OFF_ESR 288143872ull

extern "C" void kernel_launch(void* const* d_in, const int* in_sizes, int n_in,
                              void* d_out, int out_size, void* d_ws, size_t ws_size,
                              hipStream_t stream) {
  const float* x = (const float*)d_in[0];
  const int ei = (in_sizes[1] == 2 * EDGES) ? 1 : 16;
  const int base = (ei == 1) ? 2 : 1;
  const float *W[3], *AS[3], *AT[3], *SK[3], *B[3];
  for (int l = 0; l < 3; ++l) {
    W[l]  = (const float*)d_in[base + 5 * l + 0];
    AS[l] = (const float*)d_in[base + 5 * l + 1];
    AT[l] = (const float*)d_in[base + 5 * l + 2];
    SK[l] = (const float*)d_in[base + 5 * l + 3];
    B[l]  = (const float*)d_in[base + 5 * l + 4];
  }
  const int* edges = (const int*)d_in[ei];
  const int* srcv = edges;
  const int* tgtv = edges + EDGES;
  float* out = (float*)d_out;

  char* ws = (char*)d_ws;
  u16* xbf = (u16*)(ws + OFF_XBF);
  u16* Cb  = (u16*)(ws + OFF_CB);
  u16* WT  = (u16*)(ws + OFF_WT);
  int* partial = (int*)(ws + OFF_WT);    // aliases WT: live only during CSR build (before first prep)
  float* ss  = (float*)(ws + OFF_SS);
  float* stg = (float*)(ws + OFF_ST);
  int* rp  = (int*)(ws + OFF_RP);
  int* cur = (int*)(ws + OFF_CUR);
  int* esr = (int*)(ws + OFF_ESR);

  // CSR build
  hipMemsetAsync(cur, 0, NODES * sizeof(int), stream);
  hist_k<<<(EDGES + 255) / 256, 256, 0, stream>>>(tgtv, cur);
  scan1_k<<<SCAN_B, 1024, 0, stream>>>(cur, rp, partial);
  scan2_k<<<1, 64, 0, stream>>>(partial, rp + NODES);
  scan3_k<<<SCAN_B, 1024, 0, stream>>>(rp, partial, cur);
  scatter_k<<<(EDGES + 255) / 256, 256, 0, stream>>>(srcv, tgtv, cur, esr);

  convert_x_k<<<45024, 256, 0, stream>>>(x, xbf);

  for (int l = 0; l < 3; ++l) {
    const int nbx = (l < 2) ? 12 : 7;
    const int ncat = nbx * 128;
    if (l < 2)
      prep_wcat_k<0><<<dim3(48, 24), 256, 0, stream>>>(W[l], SK[l], WT);
    else
      prep_wcat_k<1><<<dim3(28, 24), 256, 0, stream>>>(W[l], SK[l], WT);
    gemm_k<<<nbx * 469, 256, 0, stream>>>(xbf, WT, Cb, AS[l], AT[l], ss, stg, nbx, ncat);
    if (l < 2)
      aggregate_k<0><<<15000, 256, 0, stream>>>(Cb, rp, esr, ss, stg, B[l], xbf, nullptr);
    else
      aggregate_k<1><<<15000, 256, 0, stream>>>(Cb, rp, esr, ss, stg, B[l], nullptr, out);
  }
}

// Round 14
// 844.878 us; speedup vs baseline: 1.0274x; 1.0274x over previous
//
#include <hip/hip_runtime.h>
#include <stdint.h>

#define NODES 60000
#define NPAD  60032   // 469 * 128
#define EDGES 240000
#define KDIM  768
#define HF    768     // HEADS * F_OUT
#define FOUT  128
#define SCAN_B 59     // ceil(NODES/1024)

typedef unsigned short u16;
typedef __bf16 bf16x8 __attribute__((ext_vector_type(8)));
typedef float f32x4 __attribute__((ext_vector_type(4)));

__device__ __forceinline__ float bf2f(u16 u) {
  union { uint32_t i; float f; } v; v.i = ((uint32_t)u) << 16; return v.f;
}
__device__ __forceinline__ u16 f2bf(float f) {
  union { float f; uint32_t i; } v; v.f = f;
  return (u16)((v.i + 0x7FFF + ((v.i >> 16) & 1)) >> 16);
}

// ---------------- convert x (f32 -> bf16, zero pad rows) ----------------
__global__ __launch_bounds__(256) void convert_x_k(const float* __restrict__ x, u16* __restrict__ xb) {
  const size_t g = ((size_t)blockIdx.x * 256 + threadIdx.x) * 4;
  if (g >= (size_t)NPAD * KDIM) return;
  ushort4 o;
  if (g < (size_t)NODES * KDIM) {
    const float4 v = *(const float4*)(x + g);
    o.x = f2bf(v.x); o.y = f2bf(v.y); o.z = f2bf(v.z); o.w = f2bf(v.w);
  } else { o.x = o.y = o.z = o.w = 0; }
  *(ushort4*)(xb + g) = o;
}

// ---------------- weight prep (LDS-tiled transpose) ----------------
// MODE 0: WT[n][k] = [W | skip][k][n], n<1536
// MODE 1: WT[n][k] = n<768 ? W[k][n] : mean_h skip[k][h*128 + (n-768)], n<896
template <int MODE>
__global__ __launch_bounds__(256) void prep_wcat_k(const float* __restrict__ W, const float* __restrict__ SK,
                                                   u16* __restrict__ WT) {
  __shared__ u16 tile[32][33];
  const int n0 = blockIdx.x * 32, k0 = blockIdx.y * 32;
  const int tx = threadIdx.x & 31, ty = threadIdx.x >> 5;  // 32 x 8
#pragma unroll
  for (int r = 0; r < 32; r += 8) {
    const int k = k0 + ty + r, n = n0 + tx;
    float v;
    if (n < HF) {
      v = W[(size_t)k * HF + n];
    } else if (MODE == 0) {
      v = SK[(size_t)k * HF + (n - HF)];
    } else {
      const int f = n - HF;
      v = 0.f;
#pragma unroll
      for (int h = 0; h < 6; ++h) v += SK[(size_t)k * HF + h * FOUT + f];
      v *= (1.0f / 6.0f);
    }
    tile[ty + r][tx] = f2bf(v);
  }
  __syncthreads();
#pragma unroll
  for (int r = 0; r < 32; r += 8) {
    const int n = n0 + ty + r, k = k0 + tx;
    WT[(size_t)n * KDIM + k] = tile[tx][ty + r];
  }
}

// ---------------- CSR build ----------------
__global__ __launch_bounds__(256) void hist_k(const int* __restrict__ tgt, int* __restrict__ deg) {
  const int e = blockIdx.x * 256 + threadIdx.x;
  if (e < EDGES) atomicAdd(&deg[tgt[e]], 1);
}

// 3-kernel coalesced scan: per-block Hillis-Steele -> scan block totals -> add offsets
__global__ __launch_bounds__(1024) void scan1_k(const int* __restrict__ deg, int* __restrict__ rp,
                                                int* __restrict__ partial) {
  __shared__ int buf[1024];
  const int tid = threadIdx.x;
  const int i = blockIdx.x * 1024 + tid;
  const int v = (i < NODES) ? deg[i] : 0;
  buf[tid] = v;
  __syncthreads();
  for (int off = 1; off < 1024; off <<= 1) {
    const int t = (tid >= off) ? buf[tid - off] : 0;
    __syncthreads();
    buf[tid] += t;
    __syncthreads();
  }
  if (i < NODES) rp[i] = buf[tid] - v;  // local exclusive
  if (tid == 1023) partial[blockIdx.x] = buf[1023];
}

__global__ __launch_bounds__(64) void scan2_k(int* __restrict__ partial, int* __restrict__ rpN) {
  __shared__ int buf[64];
  const int tid = threadIdx.x;
  const int v = (tid < SCAN_B) ? partial[tid] : 0;
  buf[tid] = v;
  __syncthreads();
  for (int off = 1; off < 64; off <<= 1) {
    const int t = (tid >= off) ? buf[tid - off] : 0;
    __syncthreads();
    buf[tid] += t;
    __syncthreads();
  }
  if (tid < SCAN_B) partial[tid] = buf[tid] - v;  // exclusive block offsets
  if (tid == 63) *rpN = buf[63];                  // total edge count
}

__global__ __launch_bounds__(1024) void scan3_k(int* __restrict__ rp, const int* __restrict__ partial,
                                                int* __restrict__ cur) {
  const int i = blockIdx.x * 1024 + threadIdx.x;
  if (i < NODES) {
    const int v = rp[i] + partial[blockIdx.x];
    rp[i] = v;
    cur[i] = v;
  }
}

__global__ __launch_bounds__(256) void scatter_k(const int* __restrict__ srcv, const int* __restrict__ tgt,
                                                 int* __restrict__ cur, int* __restrict__ esrc) {
  const int e = blockIdx.x * 256 + threadIdx.x;
  if (e < EDGES) {
    const int t = tgt[e];
    const int pos = atomicAdd(&cur[t], 1);
    esrc[pos] = srcv[e];
  }
}

// ---------------- bf16 MFMA GEMM + fused attention-score epilogue (R4/R10-proven) ----------------
// 128x128 block, 4 waves (2x2 of 64x64). VGPR 64 + 64 AGPR = 128 -> 4 waves/SIMD.
// LDS-read-BW bound at this geometry; structure ceiling (651 TF).
__global__ __launch_bounds__(256, 4) void gemm_k(const u16* __restrict__ A, const u16* __restrict__ BT,
                                                 u16* __restrict__ C,
                                                 const float* __restrict__ a_src, const float* __restrict__ a_tgt,
                                                 float* __restrict__ ss, float* __restrict__ stg,
                                                 int nbx, int ncat) {
  __shared__ u16 As[2][4096];
  __shared__ u16 Bs[2][4096];
  float* sp = (float*)&As[0][0];
  const int tid = threadIdx.x;
  const int lane = tid & 63;
  const int w = tid >> 6;
  const int wm = w >> 1, wn = w & 1;
  const int r16 = lane & 15, g4 = lane >> 4;

  const int NWG = nbx * 469;
  const int q = NWG >> 3, rr = NWG & 7;
  const int orig = blockIdx.x;
  const int xcd = orig & 7, idx = orig >> 3;
  const int wg = (xcd < rr ? xcd * (q + 1) : rr * (q + 1) + (xcd - rr) * q) + idx;
  const int bx = wg % nbx, by = wg / nbx;

  const size_t rowBase = (size_t)by * 128;
  const int colBase = bx * 128;

  const int c0 = tid, c1 = tid + 256;
  const size_t aoff0 = (rowBase + (c0 >> 2)) * KDIM + (c0 & 3) * 8;
  const size_t aoff1 = (rowBase + (c1 >> 2)) * KDIM + (c1 & 3) * 8;
  const size_t boff0 = ((size_t)(colBase + (c0 >> 2))) * KDIM + (c0 & 3) * 8;
  const size_t boff1 = ((size_t)(colBase + (c1 >> 2))) * KDIM + (c1 & 3) * 8;

  auto stage = [&](int buf, int k0) {
    __builtin_amdgcn_global_load_lds((__attribute__((address_space(1))) void*)(A + aoff0 + k0),
                                     (__attribute__((address_space(3))) void*)(&As[buf][w * 512]), 16, 0, 0);
    __builtin_amdgcn_global_load_lds((__attribute__((address_space(1))) void*)(A + aoff1 + k0),
                                     (__attribute__((address_space(3))) void*)(&As[buf][2048 + w * 512]), 16, 0, 0);
    __builtin_amdgcn_global_load_lds((__attribute__((address_space(1))) void*)(BT + boff0 + k0),
                                     (__attribute__((address_space(3))) void*)(&Bs[buf][w * 512]), 16, 0, 0);
    __builtin_amdgcn_global_load_lds((__attribute__((address_space(1))) void*)(BT + boff1 + k0),
                                     (__attribute__((address_space(3))) void*)(&Bs[buf][2048 + w * 512]), 16, 0, 0);
  };

  f32x4 acc[4][4];
#pragma unroll
  for (int i = 0; i < 4; ++i)
#pragma unroll
    for (int j = 0; j < 4; ++j) acc[i][j] = f32x4{0.f, 0.f, 0.f, 0.f};

  stage(0, 0);
  __syncthreads();
  for (int ks = 0; ks < 24; ++ks) {
    const int buf = ks & 1;
    if (ks < 23) stage(buf ^ 1, (ks + 1) * 32);
    bf16x8 af[4], bv[4];
#pragma unroll
    for (int i = 0; i < 4; ++i)
      af[i] = *(const bf16x8*)(&As[buf][(wm * 64 + i * 16 + r16) * 32 + g4 * 8]);
#pragma unroll
    for (int j = 0; j < 4; ++j)
      bv[j] = *(const bf16x8*)(&Bs[buf][(wn * 64 + j * 16 + r16) * 32 + g4 * 8]);
#pragma unroll
    for (int i = 0; i < 4; ++i)
#pragma unroll
      for (int j = 0; j < 4; ++j)
        acc[i][j] = __builtin_amdgcn_mfma_f32_16x16x32_bf16(af[i], bv[j], acc[i][j], 0, 0, 0);
    __syncthreads();
  }

#pragma unroll
  for (int i = 0; i < 4; ++i) {
    const size_t row0 = rowBase + wm * 64 + i * 16 + g4 * 4;
#pragma unroll
    for (int j = 0; j < 4; ++j) {
      const int col = colBase + wn * 64 + j * 16 + r16;
#pragma unroll
      for (int r = 0; r < 4; ++r)
        C[(row0 + r) * ncat + col] = f2bf(acc[i][j][r]);
    }
  }

  if (bx < 6) {
#pragma unroll
    for (int pass = 0; pass < 2; ++pass) {
      const float* av = (pass == 0) ? a_src : a_tgt;
      float a4[4];
#pragma unroll
      for (int j = 0; j < 4; ++j) a4[j] = av[bx * FOUT + wn * 64 + j * 16 + r16];
#pragma unroll
      for (int i = 0; i < 4; ++i) {
#pragma unroll
        for (int r = 0; r < 4; ++r) {
          float p = 0.f;
#pragma unroll
          for (int j = 0; j < 4; ++j) p += acc[i][j][r] * a4[j];
#pragma unroll
          for (int off = 1; off < 16; off <<= 1) p += __shfl_xor(p, off, 64);
          if (r16 == 0) {
            const int row = wm * 64 + i * 16 + g4 * 4 + r;
            sp[pass * 256 + wn * 128 + row] = p;
          }
        }
      }
    }
    __syncthreads();
    if (tid < 128) {
      const size_t row = rowBase + tid;
      if (row < NODES) {
        ss[row * 6 + bx] = sp[tid] + sp[128 + tid];
        stg[row * 6 + bx] = sp[256 + tid] + sp[384 + tid];
      }
    }
  }
}

// ---------------- fused ONLINE-softmax aggregation: one wave per target node, SINGLE edge pass ----------------
// lane covers cols {lane*4 + 256k + c : k<3, c<4}; head(col) = (lane>>5) + 2k
// Running (m,d,macc) per head; defer-max: rescale only when pair-max exceeds m+8 (ev bounded by e^8).
template <int MODE>
__global__ __launch_bounds__(256) void aggregate_k(const u16* __restrict__ Cb, const int* __restrict__ rp,
                                                   const int* __restrict__ esrc,
                                                   const float* __restrict__ ss, const float* __restrict__ stg,
                                                   const float* __restrict__ bias,
                                                   u16* __restrict__ xnext, float* __restrict__ outf) {
  constexpr int ncat = (MODE == 0) ? 1536 : 896;
  const int t = blockIdx.x * 4 + (threadIdx.x >> 6);
  const int lane = threadIdx.x & 63;
  if (t >= NODES) return;
  const int l4 = lane * 4;
  const int h0 = lane >> 5;

  const int b = rp[t], e = rp[t + 1];

  float sth[3], m[3], d[3], macc[3][4];
#pragma unroll
  for (int k = 0; k < 3; ++k) {
    sth[k] = stg[t * 6 + h0 + 2 * k];
    m[k] = -1e30f;
    d[k] = 0.f;
#pragma unroll
    for (int c = 0; c < 4; ++c) macc[k][c] = 0.f;
  }

  int j = b;
  for (; j + 1 < e; j += 2) {
    const int s0 = esrc[j], s1 = esrc[j + 1];
    const u16* pr0 = Cb + (size_t)s0 * ncat;
    const u16* pr1 = Cb + (size_t)s1 * ncat;
#pragma unroll
    for (int k = 0; k < 3; ++k) {
      const ushort4 v0 = *(const ushort4*)(pr0 + l4 + 256 * k);
      const ushort4 v1 = *(const ushort4*)(pr1 + l4 + 256 * k);
      float sc0 = ss[s0 * 6 + h0 + 2 * k] + sth[k];
      float sc1 = ss[s1 * 6 + h0 + 2 * k] + sth[k];
      sc0 = sc0 > 0.f ? sc0 : 0.2f * sc0;
      sc1 = sc1 > 0.f ? sc1 : 0.2f * sc1;
      const float pm = fmaxf(sc0, sc1);
      if (pm > m[k] + 8.f) {
        const float r = __expf(m[k] - pm);
        d[k] *= r;
        macc[k][0] *= r; macc[k][1] *= r; macc[k][2] *= r; macc[k][3] *= r;
        m[k] = pm;
      }
      const float ev0 = __expf(sc0 - m[k]);
      const float ev1 = __expf(sc1 - m[k]);
      d[k] += ev0 + ev1;
      macc[k][0] += ev0 * bf2f(v0.x) + ev1 * bf2f(v1.x);
      macc[k][1] += ev0 * bf2f(v0.y) + ev1 * bf2f(v1.y);
      macc[k][2] += ev0 * bf2f(v0.z) + ev1 * bf2f(v1.z);
      macc[k][3] += ev0 * bf2f(v0.w) + ev1 * bf2f(v1.w);
    }
  }
  if (j < e) {
    const int s0 = esrc[j];
    const u16* pr0 = Cb + (size_t)s0 * ncat;
#pragma unroll
    for (int k = 0; k < 3; ++k) {
      const ushort4 v0 = *(const ushort4*)(pr0 + l4 + 256 * k);
      float sc0 = ss[s0 * 6 + h0 + 2 * k] + sth[k];
      sc0 = sc0 > 0.f ? sc0 : 0.2f * sc0;
      if (sc0 > m[k] + 8.f) {
        const float r = __expf(m[k] - sc0);
        d[k] *= r;
        macc[k][0] *= r; macc[k][1] *= r; macc[k][2] *= r; macc[k][3] *= r;
        m[k] = sc0;
      }
      const float ev0 = __expf(sc0 - m[k]);
      d[k] += ev0;
      macc[k][0] += ev0 * bf2f(v0.x);
      macc[k][1] += ev0 * bf2f(v0.y);
      macc[k][2] += ev0 * bf2f(v0.z);
      macc[k][3] += ev0 * bf2f(v0.w);
    }
  }

  float inv[3];
#pragma unroll
  for (int k = 0; k < 3; ++k) inv[k] = 1.f / (d[k] + 1e-16f);

  if (MODE == 0) {
    const u16* sk = Cb + (size_t)t * ncat + HF;
#pragma unroll
    for (int k = 0; k < 3; ++k) {
      const ushort4 s4 = *(const ushort4*)(sk + l4 + 256 * k);
      ushort4 o;
      float v0 = macc[k][0] * inv[k] + bf2f(s4.x) + bias[l4 + 256 * k];
      float v1 = macc[k][1] * inv[k] + bf2f(s4.y) + bias[l4 + 256 * k + 1];
      float v2 = macc[k][2] * inv[k] + bf2f(s4.z) + bias[l4 + 256 * k + 2];
      float v3 = macc[k][3] * inv[k] + bf2f(s4.w) + bias[l4 + 256 * k + 3];
      o.x = f2bf(v0 > 0.f ? v0 : expm1f(v0));
      o.y = f2bf(v1 > 0.f ? v1 : expm1f(v1));
      o.z = f2bf(v2 > 0.f ? v2 : expm1f(v2));
      o.w = f2bf(v3 > 0.f ? v3 : expm1f(v3));
      *(ushort4*)(xnext + (size_t)t * HF + l4 + 256 * k) = o;
    }
  } else {
    float4 o;
    float* op = &o.x;
#pragma unroll
    for (int c = 0; c < 4; ++c) {
      const float s3 = macc[0][c] * inv[0] + macc[1][c] * inv[1] + macc[2][c] * inv[2];
      const float tot = s3 + __shfl_xor(s3, 32, 64);
      op[c] = tot * (1.0f / 6.0f);
    }
    if (lane < 32) {
      const int f = lane * 4;
      const ushort4 s4 = *(const ushort4*)(Cb + (size_t)t * ncat + HF + f);
      o.x += bf2f(s4.x) + bias[f];
      o.y += bf2f(s4.y) + bias[f + 1];
      o.z += bf2f(s4.z) + bias[f + 2];
      o.w += bf2f(s4.w) + bias[f + 3];
      *(float4*)(outf + (size_t)t * FOUT + f) = o;
    }
  }
}

// ---------------- workspace layout ----------------
#define OFF_XBF 0ull
#define OFF_CB  92209152ull
#define OFF_WT  276627456ull   // scan partials alias it during CSR build
#define OFF_SS  279023616ull
#define OFF_ST  280463616ull
#define OFF_RP  287663616ull
#define OFF_CUR 287903744ull
#define OFF_ESR 288143872ull

extern "C" void kernel_launch(void* const* d_in, const int* in_sizes, int n_in,
                              void* d_out, int out_size, void* d_ws, size_t ws_size,
                              hipStream_t stream) {
  const float* x = (const float*)d_in[0];
  const int ei = (in_sizes[1] == 2 * EDGES) ? 1 : 16;
  const int base = (ei == 1) ? 2 : 1;
  const float *W[3], *AS[3], *AT[3], *SK[3], *B[3];
  for (int l = 0; l < 3; ++l) {
    W[l]  = (const float*)d_in[base + 5 * l + 0];
    AS[l] = (const float*)d_in[base + 5 * l + 1];
    AT[l] = (const float*)d_in[base + 5 * l + 2];
    SK[l] = (const float*)d_in[base + 5 * l + 3];
    B[l]  = (const float*)d_in[base + 5 * l + 4];
  }
  const int* edges = (const int*)d_in[ei];
  const int* srcv = edges;
  const int* tgtv = edges + EDGES;
  float* out = (float*)d_out;

  char* ws = (char*)d_ws;
  u16* xbf = (u16*)(ws + OFF_XBF);
  u16* Cb  = (u16*)(ws + OFF_CB);
  u16* WT  = (u16*)(ws + OFF_WT);
  int* partial = (int*)(ws + OFF_WT);    // aliases WT: live only during CSR build (before first prep)
  float* ss  = (float*)(ws + OFF_SS);
  float* stg = (float*)(ws + OFF_ST);
  int* rp  = (int*)(ws + OFF_RP);
  int* cur = (int*)(ws + OFF_CUR);
  int* esr = (int*)(ws + OFF_ESR);

  // CSR build
  hipMemsetAsync(cur, 0, NODES * sizeof(int), stream);
  hist_k<<<(EDGES + 255) / 256, 256, 0, stream>>>(tgtv, cur);
  scan1_k<<<SCAN_B, 1024, 0, stream>>>(cur, rp, partial);
  scan2_k<<<1, 64, 0, stream>>>(partial, rp + NODES);
  scan3_k<<<SCAN_B, 1024, 0, stream>>>(rp, partial, cur);
  scatter_k<<<(EDGES + 255) / 256, 256, 0, stream>>>(srcv, tgtv, cur, esr);

  convert_x_k<<<45024, 256, 0, stream>>>(x, xbf);

  for (int l = 0; l < 3; ++l) {
    const int nbx = (l < 2) ? 12 : 7;
    const int ncat = nbx * 128;
    if (l < 2)
      prep_wcat_k<0><<<dim3(48, 24), 256, 0, stream>>>(W[l], SK[l], WT);
    else
      prep_wcat_k<1><<<dim3(28, 24), 256, 0, stream>>>(W[l], SK[l], WT);
    gemm_k<<<nbx * 469, 256, 0, stream>>>(xbf, WT, Cb, AS[l], AT[l], ss, stg, nbx, ncat);
    if (l < 2)
      aggregate_k<0><<<15000, 256, 0, stream>>>(Cb, rp, esr, ss, stg, B[l], xbf, nullptr);
    else
      aggregate_k<1><<<15000, 256, 0, stream>>>(Cb, rp, esr, ss, stg, B[l], nullptr, out);
  }
}